// Round 2
// baseline (850.144 us; speedup 1.0000x reference)
//
#include <hip/hip_runtime.h>

#define E_CONST 500000
#define N_CONST 100000

typedef __attribute__((ext_vector_type(8))) short bf16x8;
typedef __attribute__((ext_vector_type(4))) float f32x4;
typedef __attribute__((ext_vector_type(4))) unsigned u32x4;
typedef __attribute__((ext_vector_type(8))) unsigned short u16x8;
typedef __attribute__((ext_vector_type(4))) unsigned short u16x4;

// ---------------------------------------------------------------------------
// Prep: swizzle w1 (384x128) and w2 (128x128) fp32 -> bf16 MFMA B-fragments.
// B-frag for tile (kk, nn): lane l holds B[kk*32 + (l>>4)*8 + j][nn*16 + (l&15)],
// stored lane-major: ws[frag*512 + l*8 + j].  w1: frags 0..95, w2: frags 96..127.
// ---------------------------------------------------------------------------
__global__ __launch_bounds__(256) void prep_weights(const float* __restrict__ w1,
                                                    const float* __restrict__ w2,
                                                    short* __restrict__ ws) {
    int idx  = blockIdx.x * 256 + threadIdx.x;   // 0..65535
    int frag = idx >> 9;
    int r    = idx & 511;
    int lane = r >> 3, j = r & 7;
    const float* w;
    int fi;
    if (frag < 96) { w = w1; fi = frag; }
    else           { w = w2; fi = frag - 96; }
    int kk = fi >> 3, nn = fi & 7;
    int k = kk * 32 + (lane >> 4) * 8 + j;
    int n = nn * 16 + (lane & 15);
    unsigned u = __float_as_uint(w[k * 128 + n]);
    u = u + 0x7FFFu + ((u >> 16) & 1u);          // RNE to bf16
    ws[idx] = (short)(u >> 16);
}

__device__ __forceinline__ unsigned pack_bf16_trunc(float lo, float hi) {
    // dst = { hi[31:16], lo[31:16] } in one v_perm_b32
    return __builtin_amdgcn_perm(__float_as_uint(hi), __float_as_uint(lo), 0x07060302u);
}

__device__ __forceinline__ unsigned short to_bf16(float x) {
    unsigned u = __float_as_uint(x);
    u = u + 0x7FFFu + ((u >> 16) & 1u);
    return (unsigned short)(u >> 16);
}

// ---------------------------------------------------------------------------
// Fused: gather-concat -> GEMM1(384->128) -> SiLU -> GEMM2(128->128) -> LN -> +efeat
// Block: 256 thr (4 waves), 64 edges. Wave nw owns output cols [nw*32, nw*32+32).
// LDS: only hs (bf16, 18 KB) — reused for h then for y. y held in 32 VGPRs between.
// ---------------------------------------------------------------------------
__global__ __launch_bounds__(256, 4) void edge_mlp(
    const float* __restrict__ efeat, const float* __restrict__ nfeat,
    const int* __restrict__ src, const int* __restrict__ dst,
    const short* __restrict__ wsw,
    const float* __restrict__ b1, const float* __restrict__ b2,
    const float* __restrict__ gamma, const float* __restrict__ beta,
    float* __restrict__ out) {

    __shared__ short hs[64 * 136];   // 17.4 KB, bf16 tile (h, then y)
    __shared__ float mu_s[64];
    __shared__ float rs_s[64];

    const int tid   = threadIdx.x;
    const int lane  = tid & 63;
    const int nw    = tid >> 6;      // wave 0..3
    const int l15   = lane & 15;
    const int quad  = lane >> 4;     // 0..3
    const int eBase = blockIdx.x * 64;

    // ---- index prefetch: one load per lane covers the whole 64-edge block ----
    int ee = eBase + lane;
    if (ee >= E_CONST) ee = E_CONST - 1;
    const int vsrc = src[ee];
    const int vdst = dst[ee];

    const float bb1[2] = { b1[nw * 32 + l15], b1[nw * 32 + 16 + l15] };
    const float bb2[2] = { b2[nw * 32 + l15], b2[nw * 32 + 16 + l15] };

    // ---- GEMM1 + SiLU -> hs (bf16) ----
#pragma unroll 1
    for (int mt = 0; mt < 4; ++mt) {
        int e = eBase + mt * 16 + l15;
        if (e >= E_CONST) e = E_CONST - 1;          // clamp tail (stores guarded later)
        int s = __shfl(vsrc, mt * 16 + l15);
        int d = __shfl(vdst, mt * 16 + l15);
        const float* pe = efeat + (size_t)e * 128 + quad * 8;
        const float* ps = nfeat + (size_t)s * 128 + quad * 8;
        const float* pd = nfeat + (size_t)d * 128 + quad * 8;

        // issue all 24 gather loads up front
        f32x4 fa[12], fb[12];
#pragma unroll
        for (int kk = 0; kk < 12; ++kk) {
            const float* p = (kk < 4) ? (pe + kk * 32)
                           : (kk < 8) ? (ps + (kk - 4) * 32)
                                      : (pd + (kk - 8) * 32);
            fa[kk] = *(const f32x4*)p;
            fb[kk] = *(const f32x4*)(p + 4);
        }

        f32x4 acc0 = {0.f, 0.f, 0.f, 0.f}, acc1 = {0.f, 0.f, 0.f, 0.f};
#pragma unroll
        for (int kk = 0; kk < 12; ++kk) {
            u32x4 pk;
            pk.x = pack_bf16_trunc(fa[kk].x, fa[kk].y);
            pk.y = pack_bf16_trunc(fa[kk].z, fa[kk].w);
            pk.z = pack_bf16_trunc(fb[kk].x, fb[kk].y);
            pk.w = pack_bf16_trunc(fb[kk].z, fb[kk].w);
            bf16x8 a = __builtin_bit_cast(bf16x8, pk);
            bf16x8 w0 = *(const bf16x8*)(wsw + ((kk * 8 + nw * 2 + 0) * 64 + lane) * 8);
            bf16x8 w1f = *(const bf16x8*)(wsw + ((kk * 8 + nw * 2 + 1) * 64 + lane) * 8);
            acc0 = __builtin_amdgcn_mfma_f32_16x16x32_bf16(a, w0, acc0, 0, 0, 0);
            acc1 = __builtin_amdgcn_mfma_f32_16x16x32_bf16(a, w1f, acc1, 0, 0, 0);
        }
#pragma unroll
        for (int t = 0; t < 2; ++t) {
            f32x4 acc = (t == 0) ? acc0 : acc1;
            int col = nw * 32 + t * 16 + l15;
#pragma unroll
            for (int i = 0; i < 4; ++i) {
                float x  = acc[i] + bb1[t];
                float sg = __builtin_amdgcn_rcpf(1.0f + __expf(-x));
                float h  = x * sg;                               // SiLU
                int row  = mt * 16 + quad * 4 + i;               // C layout: row=quad*4+i
                hs[row * 136 + col] = (short)to_bf16(h);
            }
        }
    }
    __syncthreads();

    // ---- GEMM2 -> y regs (32 VGPRs) ----
    f32x4 y0[4], y1[4];
#pragma unroll 1
    for (int mt = 0; mt < 4; ++mt) {
        int arow = mt * 16 + l15;
        f32x4 acc0 = {0.f, 0.f, 0.f, 0.f}, acc1 = {0.f, 0.f, 0.f, 0.f};
#pragma unroll
        for (int kk = 0; kk < 4; ++kk) {
            bf16x8 a = *(const bf16x8*)(hs + arow * 136 + kk * 32 + quad * 8);
            bf16x8 w0 = *(const bf16x8*)(wsw + 49152 + ((kk * 8 + nw * 2 + 0) * 64 + lane) * 8);
            bf16x8 w1f = *(const bf16x8*)(wsw + 49152 + ((kk * 8 + nw * 2 + 1) * 64 + lane) * 8);
            acc0 = __builtin_amdgcn_mfma_f32_16x16x32_bf16(a, w0, acc0, 0, 0, 0);
            acc1 = __builtin_amdgcn_mfma_f32_16x16x32_bf16(a, w1f, acc1, 0, 0, 0);
        }
#pragma unroll
        for (int i = 0; i < 4; ++i) {
            acc0[i] += bb2[0];
            acc1[i] += bb2[1];
        }
        y0[mt] = acc0;
        y1[mt] = acc1;
    }
    __syncthreads();     // all hs (h) reads complete

    // ---- spill y (bf16) into hs for cross-wave LN + coalesced epilogue ----
#pragma unroll
    for (int mt = 0; mt < 4; ++mt) {
#pragma unroll
        for (int i = 0; i < 4; ++i) {
            int row = mt * 16 + quad * 4 + i;
            hs[row * 136 + nw * 32 + l15]      = (short)to_bf16(y0[mt][i]);
            hs[row * 136 + nw * 32 + 16 + l15] = (short)to_bf16(y1[mt][i]);
        }
    }
    __syncthreads();

    // ---- LayerNorm stats: 4 threads per row ----
    {
        int row = tid >> 2;
        int part = tid & 3;
        const unsigned short* yr = (const unsigned short*)hs + row * 136 + part * 32;
        float sum = 0.f, sq = 0.f;
#pragma unroll
        for (int k = 0; k < 4; ++k) {
            u16x8 v = *(const u16x8*)(yr + k * 8);
#pragma unroll
            for (int j = 0; j < 8; ++j) {
                float f = __uint_as_float((unsigned)v[j] << 16);
                sum += f;
                sq  += f * f;
            }
        }
        sum += __shfl_xor(sum, 1); sq += __shfl_xor(sq, 1);
        sum += __shfl_xor(sum, 2); sq += __shfl_xor(sq, 2);
        if (part == 0) {
            float mu  = sum * (1.0f / 128.0f);
            float var = sq * (1.0f / 128.0f) - mu * mu;
            mu_s[row] = mu;
            rs_s[row] = __builtin_amdgcn_rsqf(var + 1e-5f);
        }
    }
    __syncthreads();

    // ---- normalize + gamma/beta + residual, coalesced float4 stores ----
    {
        int c4 = tid & 31;                       // constant per thread across iters
        f32x4 g4  = *(const f32x4*)(gamma + c4 * 4);
        f32x4 bt4 = *(const f32x4*)(beta  + c4 * 4);
#pragma unroll 1
        for (int it = 0; it < 8; ++it) {
            int row = it * 8 + (tid >> 5);
            int e = eBase + row;
            if (e < E_CONST) {
                float mu = mu_s[row], rs = rs_s[row];
                u16x4 yv = *(const u16x4*)((const unsigned short*)hs + row * 136 + c4 * 4);
                f32x4 ef = *(const f32x4*)(efeat + (size_t)e * 128 + c4 * 4);
                f32x4 o;
                o.x = (__uint_as_float((unsigned)yv.x << 16) - mu) * rs * g4.x + bt4.x + ef.x;
                o.y = (__uint_as_float((unsigned)yv.y << 16) - mu) * rs * g4.y + bt4.y + ef.y;
                o.z = (__uint_as_float((unsigned)yv.z << 16) - mu) * rs * g4.z + bt4.z + ef.z;
                o.w = (__uint_as_float((unsigned)yv.w << 16) - mu) * rs * g4.w + bt4.w + ef.w;
                *(f32x4*)(out + (size_t)e * 128 + c4 * 4) = o;
            }
        }
    }
}

extern "C" void kernel_launch(void* const* d_in, const int* in_sizes, int n_in,
                              void* d_out, int out_size, void* d_ws, size_t ws_size,
                              hipStream_t stream) {
    const float* efeat = (const float*)d_in[0];
    const float* nfeat = (const float*)d_in[1];
    const int*   src   = (const int*)d_in[2];
    const int*   dst   = (const int*)d_in[3];
    const float* w1    = (const float*)d_in[4];
    const float* b1    = (const float*)d_in[5];
    const float* w2    = (const float*)d_in[6];
    const float* b2    = (const float*)d_in[7];
    const float* gamma = (const float*)d_in[8];
    const float* beta  = (const float*)d_in[9];
    float* out = (float*)d_out;
    short* wsw = (short*)d_ws;

    hipLaunchKernelGGL(prep_weights, dim3(256), dim3(256), 0, stream, w1, w2, wsw);
    // nfeat passthrough (second tuple output) via DMA engine
    hipMemcpyAsync(out + (size_t)E_CONST * 128, nfeat,
                   (size_t)N_CONST * 128 * sizeof(float),
                   hipMemcpyDeviceToDevice, stream);
    hipLaunchKernelGGL(edge_mlp, dim3((E_CONST + 63) / 64), dim3(256), 0, stream,
                       efeat, nfeat, src, dst, wsw, b1, b2, gamma, beta, out);
}